// Round 1
// 586.166 us; speedup vs baseline: 1.1427x; 1.1427x over previous
//
#include <hip/hip_runtime.h>
#include <stdint.h>

typedef unsigned short u16;
typedef unsigned int u32;
typedef __attribute__((ext_vector_type(8))) short bf16x8;
typedef __attribute__((ext_vector_type(4))) float f32x4;

__device__ __forceinline__ float bf2f(u16 u) {
    unsigned v = ((unsigned)u) << 16;
    float f;
    __builtin_memcpy(&f, &v, 4);
    return f;
}
__device__ __forceinline__ u16 f2bf(float f) {
    unsigned x;
    __builtin_memcpy(&x, &f, 4);
    unsigned r = (x + 0x7fffu + ((x >> 16) & 1u)) >> 16;
    return (u16)r;
}

#define GLDS(g, l) __builtin_amdgcn_global_load_lds( \
    (const __attribute__((address_space(1))) void*)(g), \
    (__attribute__((address_space(3))) void*)(l), 16, 0, 0)

#define BARX() do { asm volatile("" ::: "memory"); __builtin_amdgcn_s_barrier(); asm volatile("" ::: "memory"); } while (0)
#define LGKM0() asm volatile("s_waitcnt lgkmcnt(0)" ::: "memory")
#define WAIT_VM4() asm volatile("s_waitcnt vmcnt(4)" ::: "memory")
#define WAIT_VM0() asm volatile("s_waitcnt vmcnt(0)" ::: "memory")

// ============ 256x256 / BK=64 8-phase GEMM core (T2+T3+T4+T5) ============
// C = A @ B^T.  A: [M][ldk] bf16 row-major, B: [N][ldk] bf16 row-major.
// 512 threads = 8 waves (2 M x 4 N); per-wave output 128x64; acc[8][4].
// LDS: 2 bufs x { A 256x64, B 256x64 } bf16 = 128 KiB.
// T2: 16B-slot XOR-swizzle (slot ^= row&7) realized as pre-swizzled GLOBAL
// source (LDS dest of global_load_lds must stay linear) + swizzled ds_read.
// Schedule per K-tile u (4 phases, 2 barriers each, counted vmcnt once):
//   ph1: rd A-mh0(8) + B-nh0(4); issue A-h0(u+1)->other buf; MFMA quad(0,0)
//   ph2: rd B-nh1(4);            issue A-h1(u+1)->other buf; MFMA quad(0,1)
//   ph3: rd A-mh1(8);            issue B-h0(u+2)->this buf;  MFMA quad(1,1)
//   ph4: (no reads);             issue B-h1(u+2)->this buf;  MFMA quad(1,0)
//        then s_waitcnt vmcnt(4)  (tile u+1 fully landed; B(u+2) in flight)
__device__ __forceinline__ void gemm256_core(
    const u16* gA, const u16* gB, size_t ldk, int NT,
    u16* lds, int tid, f32x4 (&acc)[8][4])
{
    const int lane  = tid & 63;
    const int wave  = tid >> 6;
    const int wr    = wave >> 2;      // 0..1
    const int wc    = wave & 3;       // 0..3
    const int mlane = lane & 15;
    const int quad  = lane >> 4;
    const int swz   = mlane & 7;

    u16* A0 = lds;
    u16* B0 = lds + 16384;
    u16* A1 = lds + 32768;
    u16* B1 = lds + 49152;

    // staging: half h (128 rows) of K-tile t; 2 issues x (512 lanes x 16B)
    #define ST_A(h, t, dst) do { \
        GLDS(gA + (size_t)((h)*128     ) * ldk + (size_t)(t) * 64, (dst) + (h)*8192 + tid*8); \
        GLDS(gA + (size_t)((h)*128 + 64) * ldk + (size_t)(t) * 64, (dst) + (h)*8192 + 4096 + tid*8); \
    } while (0)
    #define ST_B(h, t, dst) do { \
        GLDS(gB + (size_t)((h)*128     ) * ldk + (size_t)(t) * 64, (dst) + (h)*8192 + tid*8); \
        GLDS(gB + (size_t)((h)*128 + 64) * ldk + (size_t)(t) * 64, (dst) + (h)*8192 + 4096 + tid*8); \
    } while (0)
    // swizzled fragment reads (byte = row*128 + ((kslot^swz)*16))
    #define RDA(mh) \
        _Pragma("unroll") \
        for (int m = 0; m < 4; ++m) { \
            const int rA = wr*128 + ((mh)*4 + m)*16 + mlane; \
            a[m][0] = *(const bf16x8*)(bA + rA*64 + (((0 + quad) ^ swz) * 8)); \
            a[m][1] = *(const bf16x8*)(bA + rA*64 + (((4 + quad) ^ swz) * 8)); \
        }
    #define RDB(nh) \
        _Pragma("unroll") \
        for (int n = 0; n < 2; ++n) { \
            const int rB = wc*64 + ((nh)*2 + n)*16 + mlane; \
            b[(nh)*2 + n][0] = *(const bf16x8*)(bB + rB*64 + (((0 + quad) ^ swz) * 8)); \
            b[(nh)*2 + n][1] = *(const bf16x8*)(bB + rB*64 + (((4 + quad) ^ swz) * 8)); \
        }
    #define MFMA_QUAD(MB, NB) do { \
        __builtin_amdgcn_s_setprio(1); \
        _Pragma("unroll") \
        for (int m = 0; m < 4; ++m) \
            _Pragma("unroll") \
            for (int n = 0; n < 2; ++n) \
                _Pragma("unroll") \
                for (int k = 0; k < 2; ++k) \
                    acc[(MB) + m][(NB) + n] = __builtin_amdgcn_mfma_f32_16x16x32_bf16( \
                        a[m][k], b[(NB) + n][k], acc[(MB) + m][(NB) + n], 0, 0, 0); \
        __builtin_amdgcn_s_setprio(0); \
    } while (0)

    // prologue: tile0 fully + tile1 B halves (A halves of tile1 come from
    // tile0's ph1/ph2 per the steady-state ledger)
    ST_A(0, 0, A0); ST_A(1, 0, A0);
    ST_B(0, 0, B0); ST_B(1, 0, B0);
    ST_B(0, 1, B1); ST_B(1, 1, B1);
    WAIT_VM4();            // tile0's 8 loads landed; tile1 B may be in flight
    BARX();

    bf16x8 a[4][2], b[4][2];

    for (int u = 0; u < NT; ++u) {
        u16* bA = (u & 1) ? A1 : A0;
        u16* bB = (u & 1) ? B1 : B0;
        u16* oA = (u & 1) ? A0 : A1;

        // ---- phase 1: quadrant (mh0, nh0); 12 ds_reads
        RDA(0);
        RDB(0);
        if (u + 1 < NT) ST_A(0, u + 1, oA);
        BARX(); LGKM0();
        MFMA_QUAD(0, 0);
        BARX();

        // ---- phase 2: quadrant (mh0, nh1); 4 ds_reads
        RDB(1);
        if (u + 1 < NT) ST_A(1, u + 1, oA);
        BARX(); LGKM0();
        MFMA_QUAD(0, 2);
        BARX();

        // ---- phase 3: quadrant (mh1, nh1); 8 ds_reads
        RDA(1);
        if (u + 2 < NT) ST_B(0, u + 2, bB);   // B region last read in ph2
        BARX(); LGKM0();
        MFMA_QUAD(4, 2);
        BARX();

        // ---- phase 4: quadrant (mh1, nh0); 0 ds_reads (b[0..1] still live)
        if (u + 2 < NT) ST_B(1, u + 2, bB);
        BARX(); LGKM0();
        MFMA_QUAD(4, 0);
        if (u + 2 < NT) { WAIT_VM4(); } else { WAIT_VM0(); }
        BARX();
    }
    #undef ST_A
    #undef ST_B
    #undef RDA
    #undef RDB
    #undef MFMA_QUAD
}

// ---------------- GEMM1: Y = relu2(X @ U^T + b), bf16 out ----------------
__global__ __launch_bounds__(512, 2) void gemm1_8ph(
    const u16* __restrict__ X, const u16* __restrict__ U1, const u16* __restrict__ U2,
    const float* __restrict__ bias1, const float* __restrict__ bias2,
    u16* __restrict__ Y1, u16* __restrict__ Y2)
{
    __shared__ __align__(16) u16 lds[65536];   // 128 KiB
    const int tid = threadIdx.x;
    const int z = blockIdx.z;
    const int rowBase = blockIdx.y * 256;
    const int colBase = blockIdx.x * 256;
    const int r0 = tid >> 3;
    const int cs = ((tid & 7) ^ (r0 & 7)) * 8;   // pre-swizzled source slot
    const u16* gA = X + (size_t)(rowBase + r0) * 1024 + cs;
    const u16* gB = (z ? U2 : U1) + (size_t)(colBase + r0) * 1024 + cs;

    f32x4 acc[8][4] = {};
    gemm256_core(gA, gB, 1024, 16, lds, tid, acc);

    const float* bias = z ? bias2 : bias1;
    u16* outp = z ? Y2 : Y1;
    const int coloff = z * 3072;
    const int lane = tid & 63, wave = tid >> 6;
    const int wr = wave >> 2, wc = wave & 3;
    const int mlane = lane & 15, quad = lane >> 4;
    #pragma unroll
    for (int n = 0; n < 4; ++n) {
        const int col = colBase + wc * 64 + n * 16 + mlane;
        const float bv = bias[col];
        #pragma unroll
        for (int m = 0; m < 8; ++m) {
            const int rb = rowBase + wr * 128 + m * 16 + quad * 4;
            #pragma unroll
            for (int r = 0; r < 4; ++r) {
                float v = acc[m][n][r] + bv;
                v = (v > 0.0f) ? v * v : 0.0f;
                outp[(size_t)(rb + r) * 6656 + coloff + col] = f2bf(v);
            }
        }
    }
}

// ---------------- GEMM2: out = Y @ W^T, f32 out, split-K=2 ----------------
__global__ __launch_bounds__(512, 2) void gemm2_8ph(
    const u16* __restrict__ Y1, const u16* __restrict__ Y2,
    const u16* __restrict__ W1, const u16* __restrict__ W2,
    float* __restrict__ out, float* __restrict__ part, int nsplit)
{
    __shared__ __align__(16) u16 lds[65536];
    const int tid = threadIdx.x;
    const int z2 = blockIdx.z;
    const int z = z2 & 1;
    const int split = z2 >> 1;
    const int Ks = 6656 / nsplit;
    const int kbeg = split * Ks;
    const int rowBase = blockIdx.y * 256;
    const int colBase = blockIdx.x * 256;
    const int r0 = tid >> 3;
    const int cs = ((tid & 7) ^ (r0 & 7)) * 8;
    const u16* gA = (z ? Y2 : Y1) + (size_t)(rowBase + r0) * 6656 + kbeg + cs;
    const u16* gB = (z ? W2 : W1) + (size_t)(colBase + r0) * 6656 + kbeg + cs;

    f32x4 acc[8][4] = {};
    gemm256_core(gA, gB, 6656, Ks >> 6, lds, tid, acc);

    float* dst = split ? part : out;
    const int coloff = z * 512;
    const int lane = tid & 63, wave = tid >> 6;
    const int wr = wave >> 2, wc = wave & 3;
    const int mlane = lane & 15, quad = lane >> 4;
    #pragma unroll
    for (int n = 0; n < 4; ++n) {
        const int col = colBase + wc * 64 + n * 16 + mlane;
        #pragma unroll
        for (int m = 0; m < 8; ++m) {
            const int rb = rowBase + wr * 128 + m * 16 + quad * 4;
            #pragma unroll
            for (int r = 0; r < 4; ++r)
                dst[(size_t)(rb + r) * 1024 + coloff + col] = acc[m][n][r];
        }
    }
}

__global__ __launch_bounds__(256) void reduce_add(
    float4* __restrict__ out, const float4* __restrict__ p, int nadd)
{
    const int i = blockIdx.x * 256 + threadIdx.x;
    float4 v = out[i];
    for (int k = 0; k < nadd; ++k) {
        const float4 a = p[(size_t)k * 2097152 + i];
        v.x += a.x; v.y += a.y; v.z += a.z; v.w += a.w;
    }
    out[i] = v;
}

__global__ __launch_bounds__(256) void cvt_bf16(
    const float* __restrict__ x, const float* __restrict__ u1,
    const float* __restrict__ u2, u16* __restrict__ dst)
{
    const int idx4 = blockIdx.x * 256 + threadIdx.x;
    const int NX = 8388608 / 4, NU = 3145728 / 4;
    const float4* src;
    int off;
    if (idx4 < NX)           { src = (const float4*)x;  off = idx4; }
    else if (idx4 < NX + NU) { src = (const float4*)u1; off = idx4 - NX; }
    else                     { src = (const float4*)u2; off = idx4 - NX - NU; }
    const float4 v = src[off];
    ushort4 o;
    o.x = f2bf(v.x); o.y = f2bf(v.y); o.z = f2bf(v.z); o.w = f2bf(v.w);
    ((ushort4*)dst)[idx4] = o;
}

__global__ __launch_bounds__(256) void prep_wcat(
    const float* __restrict__ v11, const float* __restrict__ v12,
    const float* __restrict__ v21, const float* __restrict__ v22,
    const float* __restrict__ b1,  const float* __restrict__ b2,
    u16* __restrict__ W1, u16* __restrict__ W2)
{
    const int idx = blockIdx.x * 256 + threadIdx.x;
    const int n = idx / 6656;
    const int k = idx - n * 6656;
    float w1, w2;
    if (k < 3072)      { w1 = v11[n * 3072 + k];        w2 = v21[n * 3072 + k]; }
    else if (k < 6144) { w1 = v12[n * 3072 + k - 3072]; w2 = v22[n * 3072 + k - 3072]; }
    else               { w1 = b1[(k - 6144) * 512 + n]; w2 = b2[(k - 6144) * 512 + n]; }
    W1[idx] = f2bf(w1);
    W2[idx] = f2bf(w2);
}

// ---------------- gating: MFMA t-matrices, no shuffle reduction ----------------
__global__ __launch_bounds__(256) void gating(
    const float* __restrict__ g1, const float* __restrict__ g2,
    u16* __restrict__ Y1, u16* __restrict__ Y2)
{
    __shared__ __align__(16) u16 sm[17408];
    __shared__ float tls[72];
    u16* g1b = sm;
    u16* xT1 = sm + 3072;
    u16* g2b = sm + 6144;
    u16* xT2 = sm + 9216;
    const int tid = threadIdx.x;
    const int wave = tid >> 6, lane = tid & 63;
    const size_t tok = blockIdx.x;
    const size_t gb = tok * 3072;
    const size_t yb = tok * 6656;

    #pragma unroll
    for (int j = 0; j < 3; ++j) {
        const int c = tid + j * 256;
        float4 a = ((const float4*)(g1 + gb))[c];
        float4 bq = ((const float4*)(g2 + gb))[c];
        ushort4 oa, ob;
        oa.x = f2bf(a.x); oa.y = f2bf(a.y); oa.z = f2bf(a.z); oa.w = f2bf(a.w);
        ob.x = f2bf(bq.x); ob.y = f2bf(bq.y); ob.z = f2bf(bq.z); ob.w = f2bf(bq.w);
        ((ushort4*)g1b)[c] = oa;
        ((ushort4*)g2b)[c] = ob;
        ushort4 xv1 = ((const ushort4*)(Y1 + yb))[c];
        ushort4 xv2 = ((const ushort4*)(Y2 + yb + 3072))[c];
        const u16 v1[4] = {xv1.x, xv1.y, xv1.z, xv1.w};
        const u16 v2[4] = {xv2.x, xv2.y, xv2.z, xv2.w};
        #pragma unroll
        for (int q = 0; q < 4; ++q) {
            const int e = c * 4 + q;
            const int i = e / 6;
            const int m = e - 6 * i;
            xT1[m * 512 + i] = v1[q];
            xT2[m * 512 + i] = v2[q];
        }
    }
    __syncthreads();

    if (wave < 2) {
        const u16* Ab = wave ? g2b : g1b;
        const u16* Bb = wave ? xT2 : xT1;
        const int fofs = (lane & 15) * 512 + (lane >> 4) * 8;
        f32x4 acc = {};
        #pragma unroll
        for (int k0 = 0; k0 < 512; k0 += 32) {
            bf16x8 af = *(const bf16x8*)(Ab + fofs + k0);
            bf16x8 bf = *(const bf16x8*)(Bb + fofs + k0);
            acc = __builtin_amdgcn_mfma_f32_16x16x32_bf16(af, bf, acc, 0, 0, 0);
        }
        const int col = lane & 15;
        const int rowb = (lane >> 4) * 4;
        float* ts = tls + wave * 36;
        #pragma unroll
        for (int r = 0; r < 4; ++r) {
            const int row = rowb + r;
            if (row < 6 && col < 6) ts[row * 6 + col] = acc[r];
        }
    }
    __syncthreads();

    const int t = tid;
    u32* Y1d = (u32*)(Y1 + yb);
    u32* Y2d = (u32*)(Y2 + yb);
    float sp1[2], sp2[2];
    #pragma unroll
    for (int e = 0; e < 2; ++e) {
        const int i = 2 * t + e;
        float g1v[6], g2v[6];
        float s1 = 0.f, s2 = 0.f;
        #pragma unroll
        for (int h = 0; h < 6; ++h) {
            g1v[h] = bf2f(g1b[h * 512 + i]); s1 += g1v[h];
            g2v[h] = bf2f(g2b[h * 512 + i]); s2 += g2v[h];
        }
        sp1[e] = s1; sp2[e] = s2;
        u32 pa1[3], pc2[3], pc1[3], pa2[3];
        #pragma unroll
        for (int mq = 0; mq < 3; ++mq) {
            u32 wa1 = 0, wc2 = 0, wc1 = 0, wa2 = 0;
            #pragma unroll
            for (int half = 0; half < 2; ++half) {
                const int m = mq * 2 + half;
                const float x1 = bf2f(xT1[m * 512 + i]);
                const float x2 = bf2f(xT2[m * 512 + i]);
                const float a1 = s1 * x1;
                const float a2 = s2 * x2;
                float c1 = 0.f, c2 = 0.f;
                #pragma unroll
                for (int h = 0; h < 6; ++h) {
                    c2 += tls[36 + h * 6 + m] * g1v[h];
                    c1 += tls[h * 6 + m] * g2v[h];
                }
                const int sh = half * 16;
                wa1 |= ((u32)f2bf(a1)) << sh;
                wc2 |= ((u32)f2bf(c2)) << sh;
                wc1 |= ((u32)f2bf(c1)) << sh;
                wa2 |= ((u32)f2bf(a2)) << sh;
            }
            pa1[mq] = wa1; pc2[mq] = wc2; pc1[mq] = wc1; pa2[mq] = wa2;
        }
        const int base = 6 * t + 3 * e;
        #pragma unroll
        for (int mq = 0; mq < 3; ++mq) {
            Y1d[base + mq]        = pa1[mq];
            Y1d[1536 + base + mq] = pc2[mq];
            Y2d[base + mq]        = pc1[mq];
            Y2d[1536 + base + mq] = pa2[mq];
        }
    }
    Y1d[3072 + t] = (u32)f2bf(sp1[0]) | (((u32)f2bf(sp1[1])) << 16);
    Y2d[3072 + t] = (u32)f2bf(sp2[0]) | (((u32)f2bf(sp2[1])) << 16);
}

extern "C" void kernel_launch(void* const* d_in, const int* in_sizes, int n_in,
                              void* d_out, int out_size, void* d_ws, size_t ws_size,
                              hipStream_t stream) {
    const float* x   = (const float*)d_in[0];
    const float* g1  = (const float*)d_in[1];
    const float* g2  = (const float*)d_in[2];
    const float* u1w = (const float*)d_in[3];
    const float* u1b = (const float*)d_in[4];
    const float* u2w = (const float*)d_in[5];
    const float* u2b = (const float*)d_in[6];
    const float* v11 = (const float*)d_in[7];
    const float* v12 = (const float*)d_in[8];
    const float* v21 = (const float*)d_in[9];
    const float* v22 = (const float*)d_in[10];
    const float* b1  = (const float*)d_in[11];
    const float* b2  = (const float*)d_in[12];
    float* out = (float*)d_out;

    u16* Y1   = (u16*)d_ws;                       // 8192*6656
    u16* Y2   = Y1 + (size_t)8192 * 6656;
    u16* xbf  = Y2 + (size_t)8192 * 6656;         // 8192*1024
    u16* u1bf = xbf + (size_t)8192 * 1024;        // 3072*1024
    u16* u2bf = u1bf + (size_t)3072 * 1024;
    u16* W1   = u2bf + (size_t)3072 * 1024;       // 512*6656
    u16* W2   = W1 + (size_t)512 * 6656;
    float* part = (float*)(W2 + (size_t)512 * 6656);

    const size_t base = (size_t)(W2 + (size_t)512 * 6656 - (u16*)d_ws) * 2;
    const size_t pbytes = (size_t)8192 * 1024 * 4;
    const int nsplit = (ws_size >= base + pbytes) ? 2 : 1;

    cvt_bf16<<<dim3(14336), 256, 0, stream>>>(x, u1w, u2w, xbf);
    prep_wcat<<<dim3(13312), 256, 0, stream>>>(v11, v12, v21, v22, b1, b2, W1, W2);

    gemm1_8ph<<<dim3(12, 32, 2), 512, 0, stream>>>(
        xbf, u1bf, u2bf, u1b, u2b, Y1, Y2);

    gating<<<dim3(8192), 256, 0, stream>>>(g1, g2, Y1, Y2);

    gemm2_8ph<<<dim3(2, 32, 2 * nsplit), 512, 0, stream>>>(
        Y1, Y2, W1, W2, out, part, nsplit);
    if (nsplit > 1)
        reduce_add<<<dim3(8192), 256, 0, stream>>>(
            (float4*)out, (const float4*)part, nsplit - 1);
}

// Round 2
// 585.991 us; speedup vs baseline: 1.1431x; 1.0003x over previous
//
#include <hip/hip_runtime.h>
#include <stdint.h>

typedef unsigned short u16;
typedef unsigned int u32;
typedef __attribute__((ext_vector_type(8))) short bf16x8;
typedef __attribute__((ext_vector_type(4))) float f32x4;

__device__ __forceinline__ float bf2f(u16 u) {
    unsigned v = ((unsigned)u) << 16;
    float f;
    __builtin_memcpy(&f, &v, 4);
    return f;
}
__device__ __forceinline__ u16 f2bf(float f) {
    unsigned x;
    __builtin_memcpy(&x, &f, 4);
    unsigned r = (x + 0x7fffu + ((x >> 16) & 1u)) >> 16;
    return (u16)r;
}

#define GLDS(g, l) __builtin_amdgcn_global_load_lds( \
    (const __attribute__((address_space(1))) void*)(g), \
    (__attribute__((address_space(3))) void*)(l), 16, 0, 0)

#define BARX() do { asm volatile("" ::: "memory"); __builtin_amdgcn_s_barrier(); asm volatile("" ::: "memory"); } while (0)
#define LGKM0() asm volatile("s_waitcnt lgkmcnt(0)" ::: "memory")
#define WAIT_VM4() asm volatile("s_waitcnt vmcnt(4)" ::: "memory")
#define WAIT_VM0() asm volatile("s_waitcnt vmcnt(0)" ::: "memory")

// ============ 256x256 / BK=64 oct-pipelined GEMM core ============
// C = A @ B^T.  A: [M][ldk] bf16 row-major, B: [N][ldk] bf16 row-major.
// 512 threads = 8 waves (2M x 4N); per-wave output 128x64; acc[8][4].
// LDS: 2 bufs x { A 256x64, B 256x64 } bf16 = 128 KiB, XOR-swizzled via
// pre-swizzled global source (LDS dest of global_load_lds stays linear).
//
// K-tile split into 8 octs of 8 MFMA, gray-code walk (mh, nh, kh):
//   o0(m0n0k0) o1(m1n0k0) o2(m1n1k0) o3(m0n1k0)
//   o4(m0n1k1) o5(m1n1k1) o6(m1n0k1) o7(m0n0k1)
// Operand sets: a0/a1 (4 frags), b0/b1 (2 frags). Each oct issues the
// NEXT oct's missing set (2..6 ds_reads) BEFORE its MFMAs, into the set
// NOT used by this oct's MFMAs (verified WAR-free). Compiler emits
// counted lgkmcnt, so reads fly under the current MFMA cluster.
// Reads/oct: {4,2,0,6,4,2,0,6}.
// Barriers: 2/tile. (1) LGKM0+BAR after o5 (all b-reads of this tile
// drained by every wave) -> ST_B into the just-read B buffer is safe.
// (2) vmcnt(4)+BAR after o7 -> A(u+1),B(u+1) landed; pre-read next o0 set.
// Staging: o4 issues A(u+1) (4 loads, other buf), o6/o7 issue B(u+2)
// (4 loads, current B buf). vmcnt never 0 in steady state.
__device__ __forceinline__ void gemm256_core(
    const u16* gA, const u16* gB, size_t ldk, int NT,
    u16* lds, int tid, f32x4 (&acc)[8][4])
{
    const int lane  = tid & 63;
    const int wave  = tid >> 6;
    const int wr    = wave >> 2;      // 0..1
    const int wc    = wave & 3;       // 0..3
    const int mlane = lane & 15;
    const int quad  = lane >> 4;
    const int swz   = mlane & 7;

    u16* A0 = lds;
    u16* B0 = lds + 16384;
    u16* A1 = lds + 32768;
    u16* B1 = lds + 49152;

    #define ST_A(h, t, dst) do { \
        GLDS(gA + (size_t)((h)*128     ) * ldk + (size_t)(t) * 64, (dst) + (h)*8192 + tid*8); \
        GLDS(gA + (size_t)((h)*128 + 64) * ldk + (size_t)(t) * 64, (dst) + (h)*8192 + 4096 + tid*8); \
    } while (0)
    #define ST_B(h, t, dst) do { \
        GLDS(gB + (size_t)((h)*128     ) * ldk + (size_t)(t) * 64, (dst) + (h)*8192 + tid*8); \
        GLDS(gB + (size_t)((h)*128 + 64) * ldk + (size_t)(t) * 64, (dst) + (h)*8192 + 4096 + tid*8); \
    } while (0)
    // swizzled fragment reads: u16 addr = row*64 + (((kh*4+quad)^swz)*8)
    #define RD_A(dst, buf, mh, kh) do { \
        _Pragma("unroll") \
        for (int m = 0; m < 4; ++m) { \
            const int r = wr*128 + ((mh)*4 + m)*16 + mlane; \
            dst[m] = *(const bf16x8*)((buf) + r*64 + ((((kh)*4 + quad) ^ swz) * 8)); \
        } \
    } while (0)
    #define RD_B(dst, buf, nh, kh) do { \
        _Pragma("unroll") \
        for (int n = 0; n < 2; ++n) { \
            const int r = wc*64 + ((nh)*2 + n)*16 + mlane; \
            dst[n] = *(const bf16x8*)((buf) + r*64 + ((((kh)*4 + quad) ^ swz) * 8)); \
        } \
    } while (0)
    #define MM8(aS, bS, MB, NB) do { \
        __builtin_amdgcn_s_setprio(1); \
        _Pragma("unroll") \
        for (int m = 0; m < 4; ++m) \
            _Pragma("unroll") \
            for (int n = 0; n < 2; ++n) \
                acc[(MB) + m][(NB) + n] = __builtin_amdgcn_mfma_f32_16x16x32_bf16( \
                    aS[m], bS[n], acc[(MB) + m][(NB) + n], 0, 0, 0); \
        __builtin_amdgcn_s_setprio(0); \
    } while (0)

    // prologue: tile0 A+B, tile1 B. (A(1) is staged during tile0's o4.)
    ST_A(0, 0, A0); ST_A(1, 0, A0);
    ST_B(0, 0, B0); ST_B(1, 0, B0);
    ST_B(0, 1, B1); ST_B(1, 1, B1);
    WAIT_VM4();            // tile0's 8 loads landed; B(1) may be in flight
    BARX();

    bf16x8 a0[4], a1[4], b0[2], b1[2];
    RD_A(a0, A0, 0, 0);    // (m0,k0)
    RD_B(b0, B0, 0, 0);    // (n0,k0)

    for (int u = 0; u < NT; ++u) {
        u16* bA = (u & 1) ? A1 : A0;
        u16* bB = (u & 1) ? B1 : B0;
        u16* oA = (u & 1) ? A0 : A1;   // A(u+1) home = next tile's A buf
        u16* nB = (u & 1) ? B0 : B1;   // next tile's B buf (holds B(u+1))

        // o0 (m0,n0,k0): prefetch a1 <- (m1,k0)
        RD_A(a1, bA, 1, 0);
        MM8(a0, b0, 0, 0);
        // o1 (m1,n0,k0): prefetch b1 <- (n1,k0)
        RD_B(b1, bB, 1, 0);
        MM8(a1, b0, 4, 0);
        // o2 (m1,n1,k0): o3 operands resident
        MM8(a1, b1, 4, 2);
        // o3 (m0,n1,k0): prefetch a1 <- (m0,k1), b0 <- (n1,k1); o3 uses a0,b1
        RD_A(a1, bA, 0, 1);
        RD_B(b0, bB, 1, 1);
        MM8(a0, b1, 0, 2);
        // o4 (m0,n1,k1) = (a1,b0): prefetch a0 <- (m1,k1); stage A(u+1)
        RD_A(a0, bA, 1, 1);
        if (u + 1 < NT) { ST_A(0, u + 1, oA); ST_A(1, u + 1, oA); }
        MM8(a1, b0, 0, 2);
        // o5 (m1,n1,k1) = (a0,b0): prefetch b1 <- (n0,k1)
        RD_B(b1, bB, 0, 1);
        MM8(a0, b0, 4, 2);
        // all b-reads of this tile drained by every wave after this:
        LGKM0();
        BARX();
        // o6 (m1,n0,k1) = (a0,b1): stage B(u+2) into the drained B buf
        if (u + 2 < NT) ST_B(0, u + 2, bB);
        MM8(a0, b1, 4, 0);
        // o7 (m0,n0,k1) = (a1,b1)
        if (u + 2 < NT) ST_B(1, u + 2, bB);
        MM8(a1, b1, 0, 0);

        if (u + 1 < NT) {
            if (u + 2 < NT) { WAIT_VM4(); } else { WAIT_VM0(); }
            BARX();
            // pre-read next tile's o0 operands (data just guaranteed landed)
            RD_A(a0, oA, 0, 0);
            RD_B(b0, nB, 0, 0);
        }
    }
    #undef ST_A
    #undef ST_B
    #undef RD_A
    #undef RD_B
    #undef MM8
}

// ---------------- GEMM1: Y = relu2(X @ U^T + b), bf16 out ----------------
__global__ __launch_bounds__(512, 2) void gemm1_8ph(
    const u16* __restrict__ X, const u16* __restrict__ U1, const u16* __restrict__ U2,
    const float* __restrict__ bias1, const float* __restrict__ bias2,
    u16* __restrict__ Y1, u16* __restrict__ Y2)
{
    __shared__ __align__(16) u16 lds[65536];   // 128 KiB
    const int tid = threadIdx.x;
    const int z = blockIdx.z;
    const int rowBase = blockIdx.y * 256;
    const int colBase = blockIdx.x * 256;
    const int r0 = tid >> 3;
    const int cs = ((tid & 7) ^ (r0 & 7)) * 8;   // pre-swizzled source slot
    const u16* gA = X + (size_t)(rowBase + r0) * 1024 + cs;
    const u16* gB = (z ? U2 : U1) + (size_t)(colBase + r0) * 1024 + cs;

    f32x4 acc[8][4] = {};
    gemm256_core(gA, gB, 1024, 16, lds, tid, acc);

    const float* bias = z ? bias2 : bias1;
    u16* outp = z ? Y2 : Y1;
    const int coloff = z * 3072;
    const int lane = tid & 63, wave = tid >> 6;
    const int wr = wave >> 2, wc = wave & 3;
    const int mlane = lane & 15, quad = lane >> 4;
    #pragma unroll
    for (int n = 0; n < 4; ++n) {
        const int col = colBase + wc * 64 + n * 16 + mlane;
        const float bv = bias[col];
        #pragma unroll
        for (int m = 0; m < 8; ++m) {
            const int rb = rowBase + wr * 128 + m * 16 + quad * 4;
            #pragma unroll
            for (int r = 0; r < 4; ++r) {
                float v = acc[m][n][r] + bv;
                v = (v > 0.0f) ? v * v : 0.0f;
                outp[(size_t)(rb + r) * 6656 + coloff + col] = f2bf(v);
            }
        }
    }
}

// ---------------- GEMM2: out = Y @ W^T, f32 out, split-K=2 ----------------
__global__ __launch_bounds__(512, 2) void gemm2_8ph(
    const u16* __restrict__ Y1, const u16* __restrict__ Y2,
    const u16* __restrict__ W1, const u16* __restrict__ W2,
    float* __restrict__ out, float* __restrict__ part, int nsplit)
{
    __shared__ __align__(16) u16 lds[65536];
    const int tid = threadIdx.x;
    const int z2 = blockIdx.z;
    const int z = z2 & 1;
    const int split = z2 >> 1;
    const int Ks = 6656 / nsplit;
    const int kbeg = split * Ks;
    const int rowBase = blockIdx.y * 256;
    const int colBase = blockIdx.x * 256;
    const int r0 = tid >> 3;
    const int cs = ((tid & 7) ^ (r0 & 7)) * 8;
    const u16* gA = (z ? Y2 : Y1) + (size_t)(rowBase + r0) * 6656 + kbeg + cs;
    const u16* gB = (z ? W2 : W1) + (size_t)(colBase + r0) * 6656 + kbeg + cs;

    f32x4 acc[8][4] = {};
    gemm256_core(gA, gB, 6656, Ks >> 6, lds, tid, acc);

    float* dst = split ? part : out;
    const int coloff = z * 512;
    const int lane = tid & 63, wave = tid >> 6;
    const int wr = wave >> 2, wc = wave & 3;
    const int mlane = lane & 15, quad = lane >> 4;
    #pragma unroll
    for (int n = 0; n < 4; ++n) {
        const int col = colBase + wc * 64 + n * 16 + mlane;
        #pragma unroll
        for (int m = 0; m < 8; ++m) {
            const int rb = rowBase + wr * 128 + m * 16 + quad * 4;
            #pragma unroll
            for (int r = 0; r < 4; ++r)
                dst[(size_t)(rb + r) * 1024 + coloff + col] = acc[m][n][r];
        }
    }
}

__global__ __launch_bounds__(256) void reduce_add(
    float4* __restrict__ out, const float4* __restrict__ p, int nadd)
{
    const int i = blockIdx.x * 256 + threadIdx.x;
    float4 v = out[i];
    for (int k = 0; k < nadd; ++k) {
        const float4 a = p[(size_t)k * 2097152 + i];
        v.x += a.x; v.y += a.y; v.z += a.z; v.w += a.w;
    }
    out[i] = v;
}

__global__ __launch_bounds__(256) void cvt_bf16(
    const float* __restrict__ x, const float* __restrict__ u1,
    const float* __restrict__ u2, u16* __restrict__ dst)
{
    const int idx4 = blockIdx.x * 256 + threadIdx.x;
    const int NX = 8388608 / 4, NU = 3145728 / 4;
    const float4* src;
    int off;
    if (idx4 < NX)           { src = (const float4*)x;  off = idx4; }
    else if (idx4 < NX + NU) { src = (const float4*)u1; off = idx4 - NX; }
    else                     { src = (const float4*)u2; off = idx4 - NX - NU; }
    const float4 v = src[off];
    ushort4 o;
    o.x = f2bf(v.x); o.y = f2bf(v.y); o.z = f2bf(v.z); o.w = f2bf(v.w);
    ((ushort4*)dst)[idx4] = o;
}

__global__ __launch_bounds__(256) void prep_wcat(
    const float* __restrict__ v11, const float* __restrict__ v12,
    const float* __restrict__ v21, const float* __restrict__ v22,
    const float* __restrict__ b1,  const float* __restrict__ b2,
    u16* __restrict__ W1, u16* __restrict__ W2)
{
    const int idx = blockIdx.x * 256 + threadIdx.x;
    const int n = idx / 6656;
    const int k = idx - n * 6656;
    float w1, w2;
    if (k < 3072)      { w1 = v11[n * 3072 + k];        w2 = v21[n * 3072 + k]; }
    else if (k < 6144) { w1 = v12[n * 3072 + k - 3072]; w2 = v22[n * 3072 + k - 3072]; }
    else               { w1 = b1[(k - 6144) * 512 + n]; w2 = b2[(k - 6144) * 512 + n]; }
    W1[idx] = f2bf(w1);
    W2[idx] = f2bf(w2);
}

// ---------------- gating: MFMA t-matrices, no shuffle reduction ----------------
__global__ __launch_bounds__(256) void gating(
    const float* __restrict__ g1, const float* __restrict__ g2,
    u16* __restrict__ Y1, u16* __restrict__ Y2)
{
    __shared__ __align__(16) u16 sm[17408];
    __shared__ float tls[72];
    u16* g1b = sm;
    u16* xT1 = sm + 3072;
    u16* g2b = sm + 6144;
    u16* xT2 = sm + 9216;
    const int tid = threadIdx.x;
    const int wave = tid >> 6, lane = tid & 63;
    const size_t tok = blockIdx.x;
    const size_t gb = tok * 3072;
    const size_t yb = tok * 6656;

    #pragma unroll
    for (int j = 0; j < 3; ++j) {
        const int c = tid + j * 256;
        float4 a = ((const float4*)(g1 + gb))[c];
        float4 bq = ((const float4*)(g2 + gb))[c];
        ushort4 oa, ob;
        oa.x = f2bf(a.x); oa.y = f2bf(a.y); oa.z = f2bf(a.z); oa.w = f2bf(a.w);
        ob.x = f2bf(bq.x); ob.y = f2bf(bq.y); ob.z = f2bf(bq.z); ob.w = f2bf(bq.w);
        ((ushort4*)g1b)[c] = oa;
        ((ushort4*)g2b)[c] = ob;
        ushort4 xv1 = ((const ushort4*)(Y1 + yb))[c];
        ushort4 xv2 = ((const ushort4*)(Y2 + yb + 3072))[c];
        const u16 v1[4] = {xv1.x, xv1.y, xv1.z, xv1.w};
        const u16 v2[4] = {xv2.x, xv2.y, xv2.z, xv2.w};
        #pragma unroll
        for (int q = 0; q < 4; ++q) {
            const int e = c * 4 + q;
            const int i = e / 6;
            const int m = e - 6 * i;
            xT1[m * 512 + i] = v1[q];
            xT2[m * 512 + i] = v2[q];
        }
    }
    __syncthreads();

    if (wave < 2) {
        const u16* Ab = wave ? g2b : g1b;
        const u16* Bb = wave ? xT2 : xT1;
        const int fofs = (lane & 15) * 512 + (lane >> 4) * 8;
        f32x4 acc = {};
        #pragma unroll
        for (int k0 = 0; k0 < 512; k0 += 32) {
            bf16x8 af = *(const bf16x8*)(Ab + fofs + k0);
            bf16x8 bf = *(const bf16x8*)(Bb + fofs + k0);
            acc = __builtin_amdgcn_mfma_f32_16x16x32_bf16(af, bf, acc, 0, 0, 0);
        }
        const int col = lane & 15;
        const int rowb = (lane >> 4) * 4;
        float* ts = tls + wave * 36;
        #pragma unroll
        for (int r = 0; r < 4; ++r) {
            const int row = rowb + r;
            if (row < 6 && col < 6) ts[row * 6 + col] = acc[r];
        }
    }
    __syncthreads();

    const int t = tid;
    u32* Y1d = (u32*)(Y1 + yb);
    u32* Y2d = (u32*)(Y2 + yb);
    float sp1[2], sp2[2];
    #pragma unroll
    for (int e = 0; e < 2; ++e) {
        const int i = 2 * t + e;
        float g1v[6], g2v[6];
        float s1 = 0.f, s2 = 0.f;
        #pragma unroll
        for (int h = 0; h < 6; ++h) {
            g1v[h] = bf2f(g1b[h * 512 + i]); s1 += g1v[h];
            g2v[h] = bf2f(g2b[h * 512 + i]); s2 += g2v[h];
        }
        sp1[e] = s1; sp2[e] = s2;
        u32 pa1[3], pc2[3], pc1[3], pa2[3];
        #pragma unroll
        for (int mq = 0; mq < 3; ++mq) {
            u32 wa1 = 0, wc2 = 0, wc1 = 0, wa2 = 0;
            #pragma unroll
            for (int half = 0; half < 2; ++half) {
                const int m = mq * 2 + half;
                const float x1 = bf2f(xT1[m * 512 + i]);
                const float x2 = bf2f(xT2[m * 512 + i]);
                const float a1 = s1 * x1;
                const float a2 = s2 * x2;
                float c1 = 0.f, c2 = 0.f;
                #pragma unroll
                for (int h = 0; h < 6; ++h) {
                    c2 += tls[36 + h * 6 + m] * g1v[h];
                    c1 += tls[h * 6 + m] * g2v[h];
                }
                const int sh = half * 16;
                wa1 |= ((u32)f2bf(a1)) << sh;
                wc2 |= ((u32)f2bf(c2)) << sh;
                wc1 |= ((u32)f2bf(c1)) << sh;
                wa2 |= ((u32)f2bf(a2)) << sh;
            }
            pa1[mq] = wa1; pc2[mq] = wc2; pc1[mq] = wc1; pa2[mq] = wa2;
        }
        const int base = 6 * t + 3 * e;
        #pragma unroll
        for (int mq = 0; mq < 3; ++mq) {
            Y1d[base + mq]        = pa1[mq];
            Y1d[1536 + base + mq] = pc2[mq];
            Y2d[base + mq]        = pc1[mq];
            Y2d[1536 + base + mq] = pa2[mq];
        }
    }
    Y1d[3072 + t] = (u32)f2bf(sp1[0]) | (((u32)f2bf(sp1[1])) << 16);
    Y2d[3072 + t] = (u32)f2bf(sp2[0]) | (((u32)f2bf(sp2[1])) << 16);
}

extern "C" void kernel_launch(void* const* d_in, const int* in_sizes, int n_in,
                              void* d_out, int out_size, void* d_ws, size_t ws_size,
                              hipStream_t stream) {
    const float* x   = (const float*)d_in[0];
    const float* g1  = (const float*)d_in[1];
    const float* g2  = (const float*)d_in[2];
    const float* u1w = (const float*)d_in[3];
    const float* u1b = (const float*)d_in[4];
    const float* u2w = (const float*)d_in[5];
    const float* u2b = (const float*)d_in[6];
    const float* v11 = (const float*)d_in[7];
    const float* v12 = (const float*)d_in[8];
    const float* v21 = (const float*)d_in[9];
    const float* v22 = (const float*)d_in[10];
    const float* b1  = (const float*)d_in[11];
    const float* b2  = (const float*)d_in[12];
    float* out = (float*)d_out;

    u16* Y1   = (u16*)d_ws;                       // 8192*6656
    u16* Y2   = Y1 + (size_t)8192 * 6656;
    u16* xbf  = Y2 + (size_t)8192 * 6656;         // 8192*1024
    u16* u1bf = xbf + (size_t)8192 * 1024;        // 3072*1024
    u16* u2bf = u1bf + (size_t)3072 * 1024;
    u16* W1   = u2bf + (size_t)3072 * 1024;       // 512*6656
    u16* W2   = W1 + (size_t)512 * 6656;
    float* part = (float*)(W2 + (size_t)512 * 6656);

    const size_t base = (size_t)(W2 + (size_t)512 * 6656 - (u16*)d_ws) * 2;
    const size_t pbytes = (size_t)8192 * 1024 * 4;
    const int nsplit = (ws_size >= base + pbytes) ? 2 : 1;

    cvt_bf16<<<dim3(14336), 256, 0, stream>>>(x, u1w, u2w, xbf);
    prep_wcat<<<dim3(13312), 256, 0, stream>>>(v11, v12, v21, v22, b1, b2, W1, W2);

    gemm1_8ph<<<dim3(12, 32, 2), 512, 0, stream>>>(
        xbf, u1bf, u2bf, u1b, u2b, Y1, Y2);

    gating<<<dim3(8192), 256, 0, stream>>>(g1, g2, Y1, Y2);

    gemm2_8ph<<<dim3(2, 32, 2 * nsplit), 512, 0, stream>>>(
        Y1, Y2, W1, W2, out, part, nsplit);
    if (nsplit > 1)
        reduce_add<<<dim3(8192), 256, 0, stream>>>(
            (float4*)out, (const float4*)part, nsplit - 1);
}